// Round 6
// baseline (210.768 us; speedup 1.0000x reference)
//
#include <hip/hip_runtime.h>

// SSIM loss: Xt, Yt are [B=16, C=1, T=20, H=256, W=256] fp32.
// Frame f = b*20 + t contiguous 65536 floats. dr[t] = max over Yt[:,:,t].
// S per 7x7 valid window (250x250/frame); out = 1 - mean(S).

#define HH 256
#define WW 256
#define OUTW 250
#define NT 20
#define NB 16
#define NFRAMES (NT * NB)        // 320
#define RPS 5                    // output rows per chain
#define PAIRS 25                 // 25 pairs x 10 rows = 250 rows/frame
#define NPAIRW (NFRAMES * PAIRS) // 8000 waves (2 chains each)
#define WPB 4                    // waves per block
#define NBLK2 (NPAIRW / WPB)     // 2000 blocks
#define NXCD 8

__device__ __forceinline__ float wave_sum(float v) {
#pragma unroll
    for (int off = 32; off > 0; off >>= 1) v += __shfl_down(v, off, 64);
    return v;
}

// ---------------- Pass 1: per-t max over Yt (quarter-frame blocks) ----------
__global__ __launch_bounds__(256) void dr_max_kernel(const float* __restrict__ Y,
                                                     float* __restrict__ dr_part) {
    int t = blockIdx.x;          // 0..19
    int bq = blockIdx.y;         // 0..63 : b = bq>>2, quarter = bq&3
    const float4* p = (const float4*)(Y + (size_t)((bq >> 2) * NT + t) * (HH * WW))
                      + (bq & 3) * 4096;
    float m = 0.f;               // inputs uniform [0,1) => non-negative
#pragma unroll 4
    for (int k = 0; k < 16; ++k) {
        float4 v = p[k * 256 + threadIdx.x];
        m = fmaxf(m, fmaxf(fmaxf(v.x, v.y), fmaxf(v.z, v.w)));
    }
#pragma unroll
    for (int off = 32; off > 0; off >>= 1) m = fmaxf(m, __shfl_down(m, off, 64));
    __shared__ float smax[4];
    int lane = threadIdx.x & 63, w = threadIdx.x >> 6;
    if (lane == 0) smax[w] = m;
    __syncthreads();
    if (threadIdx.x == 0)
        dr_part[t * 64 + bq] = fmaxf(fmaxf(smax[0], smax[1]), fmaxf(smax[2], smax[3]));
}

// ---------------- Pass 2: SSIM ------------------------------------------
// R11 (re-run; R5's bench was an infra failure, not a kernel verdict):
// TWO INDEPENDENT CHAINS (vertically adjacent 5-row strips) per wave.
// R8/R10 showed three pipes each ~40% (VALU 42, DS ~45, HBM 37) with
// concurrency pinned at ~13 waves/CU regardless of grid size => per-wave
// dependency stalls are the limiter. Two chains double issueable work per
// wave. Unlike R9 (which spilled: 2x tap results + 8 staged loads live),
// each chain's taps are consumed before the other's are produced:
// live = 2x20 moments + 32 staged + ~20 taps ~= 100 VGPR < 128 cap.
// Adjacent strips share 7/12 input rows -> duplicate prologue loads L1-hit.

// S scaled by 49^2 top & bottom (cancels): c1=2401*C1, c2=2401*C2.
__device__ __forceinline__ float ssim_px(float hx, float hy, float hxx, float hyy,
                                         float hxy, float c1, float c2) {
    const float cov = 49.0f / 48.0f;
    float hx2 = hx * hx, hy2 = hy * hy, hxy1 = hx * hy;
    float A1 = __builtin_fmaf(2.f, hxy1, c1);
    float B1 = hx2 + hy2 + c1;
    float t1 = __builtin_fmaf(49.f, hxx, -hx2);
    float t2 = __builtin_fmaf(49.f, hyy, -hy2);
    float t3 = __builtin_fmaf(49.f, hxy, -hxy1);
    float A2 = __builtin_fmaf(2.f * cov, t3, c2);
    float B2 = __builtin_fmaf(cov, t1 + t2, c2);
    return (A1 * A2) * __builtin_amdgcn_rcpf(B1 * B2);
}

// 7-tap horizontal sums for 4 consecutive output cols via cross-lane shuffles:
//   P = s.x+s.y+s.z+s.w;  P1 = P(lane+1), w1 = s.w(lane+1),
//   x2 = s.x(lane+2), y2 = s.y(lane+2)
//   o0 = P + P1 - w1; o1 = P + P1 - s.x; o2 = s.z+s.w+P1+x2; o3 = s.w+P1+x2+y2
// Lane 62: o0,o1 use lane-63 values (valid), o2,o3 masked. Lane 63: all masked.
__device__ __forceinline__ float4 taps7_shfl(float4 s) {
    float P  = (s.x + s.y) + (s.z + s.w);
    float P1 = __shfl_down(P,   1, 64);
    float w1 = __shfl_down(s.w, 1, 64);
    float x2 = __shfl_down(s.x, 2, 64);
    float y2 = __shfl_down(s.y, 2, 64);
    float base = P + P1;
    float o0 = base - w1;
    float o1 = base - s.x;
    float o2 = s.z + s.w + P1 + x2;
    float o3 = o2 - s.z + y2;          // s.w + P1 + x2 + y2
    return make_float4(o0, o1, o2, o3);
}

// slide with (xn-xo)*(xn+xo) factorization for the square moments
__device__ __forceinline__ void slide5(float4& sx, float4& sy, float4& sxx,
                                       float4& syy, float4& sxy,
                                       float4 xo, float4 yo, float4 xn, float4 yn) {
    float dx, ex, dy, ey;
    dx = xn.x - xo.x; ex = xn.x + xo.x; sx.x += dx; sxx.x = __builtin_fmaf(dx, ex, sxx.x);
    dy = yn.x - yo.x; ey = yn.x + yo.x; sy.x += dy; syy.x = __builtin_fmaf(dy, ey, syy.x);
    sxy.x += xn.x * yn.x - xo.x * yo.x;
    dx = xn.y - xo.y; ex = xn.y + xo.y; sx.y += dx; sxx.y = __builtin_fmaf(dx, ex, sxx.y);
    dy = yn.y - yo.y; ey = yn.y + yo.y; sy.y += dy; syy.y = __builtin_fmaf(dy, ey, syy.y);
    sxy.y += xn.y * yn.y - xo.y * yo.y;
    dx = xn.z - xo.z; ex = xn.z + xo.z; sx.z += dx; sxx.z = __builtin_fmaf(dx, ex, sxx.z);
    dy = yn.z - yo.z; ey = yn.z + yo.z; sy.z += dy; syy.z = __builtin_fmaf(dy, ey, syy.z);
    sxy.z += xn.z * yn.z - xo.z * yo.z;
    dx = xn.w - xo.w; ex = xn.w + xo.w; sx.w += dx; sxx.w = __builtin_fmaf(dx, ex, sxx.w);
    dy = yn.w - yo.w; ey = yn.w + yo.w; sy.w += dy; syy.w = __builtin_fmaf(dy, ey, syy.w);
    sxy.w += xn.w * yn.w - xo.w * yo.w;
}

__device__ __forceinline__ void accum7(float4& sx, float4& sy, float4& sxx,
                                       float4& syy, float4& sxy,
                                       float4 xv, float4 yv) {
    sx.x += xv.x; sx.y += xv.y; sx.z += xv.z; sx.w += xv.w;
    sy.x += yv.x; sy.y += yv.y; sy.z += yv.z; sy.w += yv.w;
    sxx.x = __builtin_fmaf(xv.x, xv.x, sxx.x); sxx.y = __builtin_fmaf(xv.y, xv.y, sxx.y);
    sxx.z = __builtin_fmaf(xv.z, xv.z, sxx.z); sxx.w = __builtin_fmaf(xv.w, xv.w, sxx.w);
    syy.x = __builtin_fmaf(yv.x, yv.x, syy.x); syy.y = __builtin_fmaf(yv.y, yv.y, syy.y);
    syy.z = __builtin_fmaf(yv.z, yv.z, syy.z); syy.w = __builtin_fmaf(yv.w, yv.w, syy.w);
    sxy.x = __builtin_fmaf(xv.x, yv.x, sxy.x); sxy.y = __builtin_fmaf(xv.y, yv.y, sxy.y);
    sxy.z = __builtin_fmaf(xv.z, yv.z, sxy.z); sxy.w = __builtin_fmaf(xv.w, yv.w, sxy.w);
}

__global__ __launch_bounds__(256, 4) void ssim_kernel(const float* __restrict__ X,
                                                      const float* __restrict__ Y,
                                                      const float* __restrict__ dr_part,
                                                      float* __restrict__ partials) {
    int w = threadIdx.x >> 6;
    int l = threadIdx.x & 63;
    // Bijective XCD swizzle (NBLK2 % 8 == 0)
    int bid = blockIdx.x;
    int swz = (bid % NXCD) * (NBLK2 / NXCD) + bid / NXCD;
    int wid = swz * WPB + w;
    int frame = wid / PAIRS;    // 0..319
    int pair  = wid % PAIRS;    // 0..24
    int t = frame % NT;
    const float4* x4 = (const float4*)(X + (size_t)frame * (HH * WW));
    const float4* y4 = (const float4*)(Y + (size_t)frame * (HH * WW));
    int c0 = 4 * l;

    // dr[t] = max of the 64 per-block partial maxes (one per lane, butterfly)
    float dr = dr_part[t * 64 + l];
#pragma unroll
    for (int off = 32; off > 0; off >>= 1) dr = fmaxf(dr, __shfl_xor(dr, off, 64));
    float c1 = 2401.f * (0.01f * dr) * (0.01f * dr);
    float c2 = 2401.f * (0.03f * dr) * (0.03f * dr);

    int rA = pair * (2 * RPS);      // chain A: output rows rA..rA+4
    int rB = rA + RPS;              // chain B: output rows rA+5..rA+9

    // prologues: vertical colsums over 7 rows for each chain
    float4 sxA = make_float4(0, 0, 0, 0), syA = sxA, sxxA = sxA, syyA = sxA, sxyA = sxA;
    float4 sxB = sxA, syB = sxA, sxxB = sxA, syyB = sxA, sxyB = sxA;
#pragma unroll
    for (int dy = 0; dy < 7; ++dy) {
        float4 xvA = x4[(rA + dy) * 64 + l];
        float4 yvA = y4[(rA + dy) * 64 + l];
        float4 xvB = x4[(rB + dy) * 64 + l];   // rows rA+5..rA+11: 2 shared w/ A (L1)
        float4 yvB = y4[(rB + dy) * 64 + l];
        accum7(sxA, syA, sxxA, syyA, sxyA, xvA, yvA);
        accum7(sxB, syB, sxxB, syyB, sxyB, xvB, yvB);
    }

    float acc = 0.f;
    for (int it = 0; it < RPS; ++it) {
        bool last = (it == RPS - 1);

        // issue both chains' slide loads up front
        float4 xoA, yoA, xnA, ynA, xoB, yoB, xnB, ynB;
        if (!last) {
            int ra = rA + it, rb = rB + it;
            xoA = x4[ra * 64 + l];       yoA = y4[ra * 64 + l];
            xnA = x4[(ra + 7) * 64 + l]; ynA = y4[(ra + 7) * 64 + l];
            xoB = x4[rb * 64 + l];       yoB = y4[rb * 64 + l];
            xnB = x4[(rb + 7) * 64 + l]; ynB = y4[(rb + 7) * 64 + l];
        }

        // chain A: taps + ssim (tap results die before chain B's are made)
        {
            float4 hx  = taps7_shfl(sxA);
            float4 hy  = taps7_shfl(syA);
            float4 hxx = taps7_shfl(sxxA);
            float4 hyy = taps7_shfl(syyA);
            float4 hxy = taps7_shfl(sxyA);
            if (c0 + 0 < OUTW) acc += ssim_px(hx.x, hy.x, hxx.x, hyy.x, hxy.x, c1, c2);
            if (c0 + 1 < OUTW) acc += ssim_px(hx.y, hy.y, hxx.y, hyy.y, hxy.y, c1, c2);
            if (c0 + 2 < OUTW) acc += ssim_px(hx.z, hy.z, hxx.z, hyy.z, hxy.z, c1, c2);
            if (c0 + 3 < OUTW) acc += ssim_px(hx.w, hy.w, hxx.w, hyy.w, hxy.w, c1, c2);
        }
        // chain B: taps + ssim
        {
            float4 hx  = taps7_shfl(sxB);
            float4 hy  = taps7_shfl(syB);
            float4 hxx = taps7_shfl(sxxB);
            float4 hyy = taps7_shfl(syyB);
            float4 hxy = taps7_shfl(sxyB);
            if (c0 + 0 < OUTW) acc += ssim_px(hx.x, hy.x, hxx.x, hyy.x, hxy.x, c1, c2);
            if (c0 + 1 < OUTW) acc += ssim_px(hx.y, hy.y, hxx.y, hyy.y, hxy.y, c1, c2);
            if (c0 + 2 < OUTW) acc += ssim_px(hx.z, hy.z, hxx.z, hyy.z, hxy.z, c1, c2);
            if (c0 + 3 < OUTW) acc += ssim_px(hx.w, hy.w, hxx.w, hyy.w, hxy.w, c1, c2);
        }

        if (!last) {
            slide5(sxA, syA, sxxA, syyA, sxyA, xoA, yoA, xnA, ynA);
            slide5(sxB, syB, sxxB, syyB, sxyB, xoB, yoB, xnB, ynB);
        }
    }

    // block-level reduction: 4 waves -> 1 partial per block
    acc = wave_sum(acc);
    __shared__ float ssum[4];
    if (l == 0) ssum[w] = acc;
    __syncthreads();
    if (threadIdx.x == 0)
        partials[blockIdx.x] = (ssum[0] + ssum[1]) + (ssum[2] + ssum[3]);
}

// ---------------- Pass 3: final reduce ----------------
__global__ __launch_bounds__(256) void final_kernel(const float* __restrict__ partials,
                                                    float* __restrict__ out) {
    float s = 0.f;
    for (int i = threadIdx.x; i < NBLK2; i += 256) s += partials[i];
    s = wave_sum(s);
    __shared__ float ssum[4];
    int lane = threadIdx.x & 63, w = threadIdx.x >> 6;
    if (lane == 0) ssum[w] = s;
    __syncthreads();
    if (threadIdx.x == 0) {
        float total = ssum[0] + ssum[1] + ssum[2] + ssum[3];
        const double denom = (double)NFRAMES * OUTW * OUTW;
        out[0] = (float)(1.0 - (double)total / denom);
    }
}

extern "C" void kernel_launch(void* const* d_in, const int* in_sizes, int n_in,
                              void* d_out, int out_size, void* d_ws, size_t ws_size,
                              hipStream_t stream) {
    const float* X = (const float*)d_in[0];
    const float* Y = (const float*)d_in[1];

    float* ws = (float*)d_ws;
    float* dr_part  = ws;                // [0 .. 1280)
    float* partials = ws + 2048;         // [2048 .. 2048+2000)

    dim3 g1(NT, NB * 4);
    hipLaunchKernelGGL(dr_max_kernel, g1, dim3(256), 0, stream, Y, dr_part);
    hipLaunchKernelGGL(ssim_kernel, dim3(NBLK2), dim3(256), 0, stream,
                       X, Y, (const float*)dr_part, partials);
    hipLaunchKernelGGL(final_kernel, dim3(1), dim3(256), 0, stream,
                       partials, (float*)d_out);
}

// Round 7
// 201.996 us; speedup vs baseline: 1.0434x; 1.0434x over previous
//
#include <hip/hip_runtime.h>

// SSIM loss: Xt, Yt are [B=16, C=1, T=20, H=256, W=256] fp32.
// Frame f = b*20 + t contiguous 65536 floats. dr[t] = max over Yt[:,:,t].
// S per 7x7 valid window (250x250/frame); out = 1 - mean(S).

#define HH 256
#define WW 256
#define OUTW 250
#define NT 20
#define NB 16
#define NFRAMES (NT * NB)        // 320
#define STRIPS 50
#define RPS 5                    // output rows per strip (50*5 = 250)
#define NWAVES (NFRAMES * STRIPS) // 16000
#define WPB 4                    // waves per block
#define NBLK2 (NWAVES / WPB)     // 4000
#define NXCD 8

__device__ __forceinline__ float wave_sum(float v) {
#pragma unroll
    for (int off = 32; off > 0; off >>= 1) v += __shfl_down(v, off, 64);
    return v;
}

// ---------------- Pass 1: per-t max over Yt (quarter-frame blocks) ----------
__global__ __launch_bounds__(256) void dr_max_kernel(const float* __restrict__ Y,
                                                     float* __restrict__ dr_part) {
    int t = blockIdx.x;          // 0..19
    int bq = blockIdx.y;         // 0..63 : b = bq>>2, quarter = bq&3
    const float4* p = (const float4*)(Y + (size_t)((bq >> 2) * NT + t) * (HH * WW))
                      + (bq & 3) * 4096;
    float m = 0.f;               // inputs uniform [0,1) => non-negative
#pragma unroll 4
    for (int k = 0; k < 16; ++k) {
        float4 v = p[k * 256 + threadIdx.x];
        m = fmaxf(m, fmaxf(fmaxf(v.x, v.y), fmaxf(v.z, v.w)));
    }
#pragma unroll
    for (int off = 32; off > 0; off >>= 1) m = fmaxf(m, __shfl_down(m, off, 64));
    __shared__ float smax[4];
    int lane = threadIdx.x & 63, w = threadIdx.x >> 6;
    if (lane == 0) smax[w] = m;
    __syncthreads();
    if (threadIdx.x == 0)
        dr_part[t * 64 + bq] = fmaxf(fmaxf(smax[0], smax[1]), fmaxf(smax[2], smax[3]));
}

// ---------------- Pass 2: SSIM ------------------------------------------
// R12: R10 geometry (best known: 52us; 1 chain/wave, 16000 waves, 4000 blocks,
// XCD swizzle) + EXPLICIT 2-DEEP LOAD PIPELINE. R11's post-mortem: compiler
// reported VGPR 64 (not ~100) => it sank the staged loads to their uses,
// exposing full memory latency every slide (VALUBusy 30%). Here slide-(it+1)'s
// loads are issued at the TOP of iteration it and pinned by a compiler-only
// memory fence (loads can't sink across it; shuffles aren't memory ops so
// taps still schedule freely). Use-distance = taps+ssim+slide+taps+ssim
// ~570 SIMD-cyc -> covers HBM latency at 3+ waves/SIMD.
// VGPR estimate: 20 moments + 16 cur + 16 nxt + ~25 temps ~= 95 < 128 cap.
// Tripwires: VGPR ~50 => staging defeated; WRITE_SIZE in MBs => spill.

// S scaled by 49^2 top & bottom (cancels): c1=2401*C1, c2=2401*C2.
__device__ __forceinline__ float ssim_px(float hx, float hy, float hxx, float hyy,
                                         float hxy, float c1, float c2) {
    const float cov = 49.0f / 48.0f;
    float hx2 = hx * hx, hy2 = hy * hy, hxy1 = hx * hy;
    float A1 = __builtin_fmaf(2.f, hxy1, c1);
    float B1 = hx2 + hy2 + c1;
    float t1 = __builtin_fmaf(49.f, hxx, -hx2);
    float t2 = __builtin_fmaf(49.f, hyy, -hy2);
    float t3 = __builtin_fmaf(49.f, hxy, -hxy1);
    float A2 = __builtin_fmaf(2.f * cov, t3, c2);
    float B2 = __builtin_fmaf(cov, t1 + t2, c2);
    return (A1 * A2) * __builtin_amdgcn_rcpf(B1 * B2);
}

// 7-tap horizontal sums for 4 consecutive output cols via cross-lane shuffles:
//   P = s.x+s.y+s.z+s.w;  P1 = P(lane+1), w1 = s.w(lane+1),
//   x2 = s.x(lane+2), y2 = s.y(lane+2)
//   o0 = P + P1 - w1; o1 = P + P1 - s.x; o2 = s.z+s.w+P1+x2; o3 = s.w+P1+x2+y2
// Lane 62: o0,o1 use lane-63 values (valid), o2,o3 masked. Lane 63: all masked.
__device__ __forceinline__ float4 taps7_shfl(float4 s) {
    float P  = (s.x + s.y) + (s.z + s.w);
    float P1 = __shfl_down(P,   1, 64);
    float w1 = __shfl_down(s.w, 1, 64);
    float x2 = __shfl_down(s.x, 2, 64);
    float y2 = __shfl_down(s.y, 2, 64);
    float base = P + P1;
    float o0 = base - w1;
    float o1 = base - s.x;
    float o2 = s.z + s.w + P1 + x2;
    float o3 = o2 - s.z + y2;          // s.w + P1 + x2 + y2
    return make_float4(o0, o1, o2, o3);
}

// slide with (xn-xo)*(xn+xo) factorization for the square moments
__device__ __forceinline__ void slide5(float4& sx, float4& sy, float4& sxx,
                                       float4& syy, float4& sxy,
                                       float4 xo, float4 yo, float4 xn, float4 yn) {
    float dx, ex, dy, ey;
    dx = xn.x - xo.x; ex = xn.x + xo.x; sx.x += dx; sxx.x = __builtin_fmaf(dx, ex, sxx.x);
    dy = yn.x - yo.x; ey = yn.x + yo.x; sy.x += dy; syy.x = __builtin_fmaf(dy, ey, syy.x);
    sxy.x += xn.x * yn.x - xo.x * yo.x;
    dx = xn.y - xo.y; ex = xn.y + xo.y; sx.y += dx; sxx.y = __builtin_fmaf(dx, ex, sxx.y);
    dy = yn.y - yo.y; ey = yn.y + yo.y; sy.y += dy; syy.y = __builtin_fmaf(dy, ey, syy.y);
    sxy.y += xn.y * yn.y - xo.y * yo.y;
    dx = xn.z - xo.z; ex = xn.z + xo.z; sx.z += dx; sxx.z = __builtin_fmaf(dx, ex, sxx.z);
    dy = yn.z - yo.z; ey = yn.z + yo.z; sy.z += dy; syy.z = __builtin_fmaf(dy, ey, syy.z);
    sxy.z += xn.z * yn.z - xo.z * yo.z;
    dx = xn.w - xo.w; ex = xn.w + xo.w; sx.w += dx; sxx.w = __builtin_fmaf(dx, ex, sxx.w);
    dy = yn.w - yo.w; ey = yn.w + yo.w; sy.w += dy; syy.w = __builtin_fmaf(dy, ey, syy.w);
    sxy.w += xn.w * yn.w - xo.w * yo.w;
}

__device__ __forceinline__ void accum7(float4& sx, float4& sy, float4& sxx,
                                       float4& syy, float4& sxy,
                                       float4 xv, float4 yv) {
    sx.x += xv.x; sx.y += xv.y; sx.z += xv.z; sx.w += xv.w;
    sy.x += yv.x; sy.y += yv.y; sy.z += yv.z; sy.w += yv.w;
    sxx.x = __builtin_fmaf(xv.x, xv.x, sxx.x); sxx.y = __builtin_fmaf(xv.y, xv.y, sxx.y);
    sxx.z = __builtin_fmaf(xv.z, xv.z, sxx.z); sxx.w = __builtin_fmaf(xv.w, xv.w, sxx.w);
    syy.x = __builtin_fmaf(yv.x, yv.x, syy.x); syy.y = __builtin_fmaf(yv.y, yv.y, syy.y);
    syy.z = __builtin_fmaf(yv.z, yv.z, syy.z); syy.w = __builtin_fmaf(yv.w, yv.w, syy.w);
    sxy.x = __builtin_fmaf(xv.x, yv.x, sxy.x); sxy.y = __builtin_fmaf(xv.y, yv.y, sxy.y);
    sxy.z = __builtin_fmaf(xv.z, yv.z, sxy.z); sxy.w = __builtin_fmaf(xv.w, yv.w, sxy.w);
}

__global__ __launch_bounds__(256, 4) void ssim_kernel(const float* __restrict__ X,
                                                      const float* __restrict__ Y,
                                                      const float* __restrict__ dr_part,
                                                      float* __restrict__ partials) {
    int w = threadIdx.x >> 6;
    int l = threadIdx.x & 63;
    // Bijective XCD swizzle (NBLK2 % 8 == 0)
    int bid = blockIdx.x;
    int swz = (bid % NXCD) * (NBLK2 / NXCD) + bid / NXCD;
    int wid = swz * WPB + w;
    int frame = wid / STRIPS;   // 0..319
    int strip = wid % STRIPS;   // 0..49
    int t = frame % NT;
    const float4* x4 = (const float4*)(X + (size_t)frame * (HH * WW));
    const float4* y4 = (const float4*)(Y + (size_t)frame * (HH * WW));
    int c0 = 4 * l;

    // dr[t] = max of the 64 per-block partial maxes (one per lane, butterfly)
    float dr = dr_part[t * 64 + l];
#pragma unroll
    for (int off = 32; off > 0; off >>= 1) dr = fmaxf(dr, __shfl_xor(dr, off, 64));
    float c1 = 2401.f * (0.01f * dr) * (0.01f * dr);
    float c2 = 2401.f * (0.03f * dr) * (0.03f * dr);

    int r0 = strip * RPS;

    // vertical running column-sums (4 cols/lane) over rows r0..r0+6
    float4 sx = make_float4(0, 0, 0, 0), sy = sx, sxx = sx, syy = sx, sxy = sx;
#pragma unroll
    for (int dy = 0; dy < 7; ++dy) {
        float4 xv = x4[(r0 + dy) * 64 + l];
        float4 yv = y4[(r0 + dy) * 64 + l];
        accum7(sx, sy, sxx, syy, sxy, xv, yv);
    }

    // stage slide-0 loads (rows r0, r0+7)
    float4 cxo = x4[r0 * 64 + l],       cyo = y4[r0 * 64 + l];
    float4 cxn = x4[(r0 + 7) * 64 + l], cyn = y4[(r0 + 7) * 64 + l];

    float acc = 0.f;
#pragma unroll
    for (int it = 0; it < RPS; ++it) {
        // stage slide-(it+1) loads one full iteration ahead of use
        float4 nxo, nyo, nxn, nyn;
        if (it < RPS - 2) {
            int rr = r0 + it + 1;
            nxo = x4[rr * 64 + l];       nyo = y4[rr * 64 + l];
            nxn = x4[(rr + 7) * 64 + l]; nyn = y4[(rr + 7) * 64 + l];
        }
        // pin load issue point: loads above cannot sink below this fence
        // (shuffles are not memory ops; taps/ssim still schedule freely)
        asm volatile("" ::: "memory");

        float4 hx  = taps7_shfl(sx);
        float4 hy  = taps7_shfl(sy);
        float4 hxx = taps7_shfl(sxx);
        float4 hyy = taps7_shfl(syy);
        float4 hxy = taps7_shfl(sxy);

        // lanes 0..61: all 4 valid; lane 62 (c0=248): 2 valid; lane 63: none
        if (c0 + 0 < OUTW) acc += ssim_px(hx.x, hy.x, hxx.x, hyy.x, hxy.x, c1, c2);
        if (c0 + 1 < OUTW) acc += ssim_px(hx.y, hy.y, hxx.y, hyy.y, hxy.y, c1, c2);
        if (c0 + 2 < OUTW) acc += ssim_px(hx.z, hy.z, hxx.z, hyy.z, hxy.z, c1, c2);
        if (c0 + 3 < OUTW) acc += ssim_px(hx.w, hy.w, hxx.w, hyy.w, hxy.w, c1, c2);

        if (it < RPS - 1)
            slide5(sx, sy, sxx, syy, sxy, cxo, cyo, cxn, cyn);
        if (it < RPS - 2) {      // rotate staged set for the next slide
            cxo = nxo; cyo = nyo; cxn = nxn; cyn = nyn;
        }
    }

    // block-level reduction: 4 waves -> 1 partial per block
    acc = wave_sum(acc);
    __shared__ float ssum[4];
    if (l == 0) ssum[w] = acc;
    __syncthreads();
    if (threadIdx.x == 0)
        partials[blockIdx.x] = (ssum[0] + ssum[1]) + (ssum[2] + ssum[3]);
}

// ---------------- Pass 3: final reduce ----------------
__global__ __launch_bounds__(256) void final_kernel(const float* __restrict__ partials,
                                                    float* __restrict__ out) {
    float s = 0.f;
    for (int i = threadIdx.x; i < NBLK2; i += 256) s += partials[i];
    s = wave_sum(s);
    __shared__ float ssum[4];
    int lane = threadIdx.x & 63, w = threadIdx.x >> 6;
    if (lane == 0) ssum[w] = s;
    __syncthreads();
    if (threadIdx.x == 0) {
        float total = ssum[0] + ssum[1] + ssum[2] + ssum[3];
        const double denom = (double)NFRAMES * OUTW * OUTW;
        out[0] = (float)(1.0 - (double)total / denom);
    }
}

extern "C" void kernel_launch(void* const* d_in, const int* in_sizes, int n_in,
                              void* d_out, int out_size, void* d_ws, size_t ws_size,
                              hipStream_t stream) {
    const float* X = (const float*)d_in[0];
    const float* Y = (const float*)d_in[1];

    float* ws = (float*)d_ws;
    float* dr_part  = ws;                // [0 .. 1280)
    float* partials = ws + 2048;         // [2048 .. 2048+4000)

    dim3 g1(NT, NB * 4);
    hipLaunchKernelGGL(dr_max_kernel, g1, dim3(256), 0, stream, Y, dr_part);
    hipLaunchKernelGGL(ssim_kernel, dim3(NBLK2), dim3(256), 0, stream,
                       X, Y, (const float*)dr_part, partials);
    hipLaunchKernelGGL(final_kernel, dim3(1), dim3(256), 0, stream,
                       partials, (float*)d_out);
}

// Round 8
// 201.127 us; speedup vs baseline: 1.0479x; 1.0043x over previous
//
#include <hip/hip_runtime.h>

// SSIM loss: Xt, Yt are [B=16, C=1, T=20, H=256, W=256] fp32.
// Frame f = b*20 + t contiguous 65536 floats. dr[t] = max over Yt[:,:,t].
// S per 7x7 valid window (250x250/frame); out = 1 - mean(S).

#define HH 256
#define WW 256
#define OUTW 250
#define NT 20
#define NB 16
#define NFRAMES (NT * NB)        // 320
#define STRIPS 50
#define RPS 5                    // output rows per strip (50*5 = 250)
#define NWAVES (NFRAMES * STRIPS) // 16000
#define WPB 4                    // waves per block
#define NBLK2 (NWAVES / WPB)     // 4000
#define NXCD 8

__device__ __forceinline__ float wave_sum(float v) {
#pragma unroll
    for (int off = 32; off > 0; off >>= 1) v += __shfl_down(v, off, 64);
    return v;
}

// ---------------- Pass 1: per-t max over Yt (quarter-frame blocks) ----------
__global__ __launch_bounds__(256) void dr_max_kernel(const float* __restrict__ Y,
                                                     float* __restrict__ dr_part) {
    int t = blockIdx.x;          // 0..19
    int bq = blockIdx.y;         // 0..63 : b = bq>>2, quarter = bq&3
    const float4* p = (const float4*)(Y + (size_t)((bq >> 2) * NT + t) * (HH * WW))
                      + (bq & 3) * 4096;
    float m = 0.f;               // inputs uniform [0,1) => non-negative
#pragma unroll 4
    for (int k = 0; k < 16; ++k) {
        float4 v = p[k * 256 + threadIdx.x];
        m = fmaxf(m, fmaxf(fmaxf(v.x, v.y), fmaxf(v.z, v.w)));
    }
#pragma unroll
    for (int off = 32; off > 0; off >>= 1) m = fmaxf(m, __shfl_down(m, off, 64));
    __shared__ float smax[4];
    int lane = threadIdx.x & 63, w = threadIdx.x >> 6;
    if (lane == 0) smax[w] = m;
    __syncthreads();
    if (threadIdx.x == 0)
        dr_part[t * 64 + bq] = fmaxf(fmaxf(smax[0], smax[1]), fmaxf(smax[2], smax[3]));
}

// ---------------- Pass 2: SSIM ------------------------------------------
// R13 = R12 geometry (best: 53us; 16000 waves, 4000 blocks, XCD swizzle,
// 2-deep staged loads) + DS/VALU issue-count cuts:
//  (a) 4 moments not 5: hxx,hyy only ever appear as 49(hxx+hyy)-hx^2-hy^2
//      in B2 => maintain sq = sxx+syy. 16 shuffles/row instead of 20.
//  (b) raw ds_bpermute with lane addresses hoisted to the prologue:
//      __shfl_down re-emits ~3 VALU (clamp+shift) per call; a1/a2 are
//      loop-invariant. Each shuffle is now exactly 1 DS op.
// Rationale: duration pinned 52-60us across 7 structures while VALU<=42%,
// HBM<=40%, occ<=42% -- the uncounted pipe is the wave64 ds_bpermute
// crossbar + its addressing VALU. Cut the op count itself.

// S scaled by 49^2 top & bottom (cancels): c1=2401*C1, c2=2401*C2.
// 4-moment form: B2 = cov*(49*hq - hx^2 - hy^2) + c2, hq = 7-tap of sxx+syy.
__device__ __forceinline__ float ssim_px4(float hx, float hy, float hq,
                                          float hxy, float c1, float c2) {
    const float cov = 49.0f / 48.0f;
    float hx2 = hx * hx, hy2 = hy * hy, hxy1 = hx * hy;
    float s2 = hx2 + hy2;
    float A1 = __builtin_fmaf(2.f, hxy1, c1);
    float B1 = s2 + c1;
    float t12 = __builtin_fmaf(49.f, hq, -s2);
    float t3  = __builtin_fmaf(49.f, hxy, -hxy1);
    float A2 = __builtin_fmaf(2.f * cov, t3, c2);
    float B2 = __builtin_fmaf(cov, t12, c2);
    return (A1 * A2) * __builtin_amdgcn_rcpf(B1 * B2);
}

__device__ __forceinline__ float bperm(int addr, float v) {
    return __int_as_float(__builtin_amdgcn_ds_bpermute(addr, __float_as_int(v)));
}

// 7-tap horizontal sums for 4 consecutive output cols; a1/a2 = byte addrs of
// lanes l+1, l+2 (clamped to 63; clamped values feed only masked outputs).
//   P = s.x+s.y+s.z+s.w;  P1 = P(l+1), w1 = s.w(l+1), x2 = s.x(l+2), y2 = s.y(l+2)
//   o0 = P+P1-w1; o1 = P+P1-s.x; o2 = s.z+s.w+P1+x2; o3 = s.w+P1+x2+y2
__device__ __forceinline__ float4 taps7_bp(float4 s, int a1, int a2) {
    float P  = (s.x + s.y) + (s.z + s.w);
    float P1 = bperm(a1, P);
    float w1 = bperm(a1, s.w);
    float x2 = bperm(a2, s.x);
    float y2 = bperm(a2, s.y);
    float base = P + P1;
    float o0 = base - w1;
    float o1 = base - s.x;
    float o2 = s.z + s.w + P1 + x2;
    float o3 = o2 - s.z + y2;          // s.w + P1 + x2 + y2
    return make_float4(o0, o1, o2, o3);
}

// slide with (xn-xo)*(xn+xo) factorization; sq accumulates xx+yy deltas
__device__ __forceinline__ void slide4(float4& sx, float4& sy, float4& sq,
                                       float4& sxy,
                                       float4 xo, float4 yo, float4 xn, float4 yn) {
    float dx, ex, dy, ey;
    dx = xn.x - xo.x; ex = xn.x + xo.x; sx.x += dx; sq.x = __builtin_fmaf(dx, ex, sq.x);
    dy = yn.x - yo.x; ey = yn.x + yo.x; sy.x += dy; sq.x = __builtin_fmaf(dy, ey, sq.x);
    sxy.x += xn.x * yn.x - xo.x * yo.x;
    dx = xn.y - xo.y; ex = xn.y + xo.y; sx.y += dx; sq.y = __builtin_fmaf(dx, ex, sq.y);
    dy = yn.y - yo.y; ey = yn.y + yo.y; sy.y += dy; sq.y = __builtin_fmaf(dy, ey, sq.y);
    sxy.y += xn.y * yn.y - xo.y * yo.y;
    dx = xn.z - xo.z; ex = xn.z + xo.z; sx.z += dx; sq.z = __builtin_fmaf(dx, ex, sq.z);
    dy = yn.z - yo.z; ey = yn.z + yo.z; sy.z += dy; sq.z = __builtin_fmaf(dy, ey, sq.z);
    sxy.z += xn.z * yn.z - xo.z * yo.z;
    dx = xn.w - xo.w; ex = xn.w + xo.w; sx.w += dx; sq.w = __builtin_fmaf(dx, ex, sq.w);
    dy = yn.w - yo.w; ey = yn.w + yo.w; sy.w += dy; sq.w = __builtin_fmaf(dy, ey, sq.w);
    sxy.w += xn.w * yn.w - xo.w * yo.w;
}

__device__ __forceinline__ void accum4(float4& sx, float4& sy, float4& sq,
                                       float4& sxy, float4 xv, float4 yv) {
    sx.x += xv.x; sx.y += xv.y; sx.z += xv.z; sx.w += xv.w;
    sy.x += yv.x; sy.y += yv.y; sy.z += yv.z; sy.w += yv.w;
    sq.x = __builtin_fmaf(xv.x, xv.x, sq.x); sq.x = __builtin_fmaf(yv.x, yv.x, sq.x);
    sq.y = __builtin_fmaf(xv.y, xv.y, sq.y); sq.y = __builtin_fmaf(yv.y, yv.y, sq.y);
    sq.z = __builtin_fmaf(xv.z, xv.z, sq.z); sq.z = __builtin_fmaf(yv.z, yv.z, sq.z);
    sq.w = __builtin_fmaf(xv.w, xv.w, sq.w); sq.w = __builtin_fmaf(yv.w, yv.w, sq.w);
    sxy.x = __builtin_fmaf(xv.x, yv.x, sxy.x); sxy.y = __builtin_fmaf(xv.y, yv.y, sxy.y);
    sxy.z = __builtin_fmaf(xv.z, yv.z, sxy.z); sxy.w = __builtin_fmaf(xv.w, yv.w, sxy.w);
}

__global__ __launch_bounds__(256, 4) void ssim_kernel(const float* __restrict__ X,
                                                      const float* __restrict__ Y,
                                                      const float* __restrict__ dr_part,
                                                      float* __restrict__ partials) {
    int w = threadIdx.x >> 6;
    int l = threadIdx.x & 63;
    // Bijective XCD swizzle (NBLK2 % 8 == 0)
    int bid = blockIdx.x;
    int swz = (bid % NXCD) * (NBLK2 / NXCD) + bid / NXCD;
    int wid = swz * WPB + w;
    int frame = wid / STRIPS;   // 0..319
    int strip = wid % STRIPS;   // 0..49
    int t = frame % NT;
    const float4* x4 = (const float4*)(X + (size_t)frame * (HH * WW));
    const float4* y4 = (const float4*)(Y + (size_t)frame * (HH * WW));
    int c0 = 4 * l;
    // hoisted bpermute byte-addresses (loop-invariant)
    int a1 = (l < 63 ? l + 1 : 63) << 2;
    int a2 = (l < 62 ? l + 2 : 63) << 2;

    // dr[t] = max of the 64 per-block partial maxes (one per lane, butterfly)
    float dr = dr_part[t * 64 + l];
#pragma unroll
    for (int off = 32; off > 0; off >>= 1) dr = fmaxf(dr, __shfl_xor(dr, off, 64));
    float c1 = 2401.f * (0.01f * dr) * (0.01f * dr);
    float c2 = 2401.f * (0.03f * dr) * (0.03f * dr);

    int r0 = strip * RPS;

    // vertical running column-sums (4 cols/lane) over rows r0..r0+6
    float4 sx = make_float4(0, 0, 0, 0), sy = sx, sq = sx, sxy = sx;
#pragma unroll
    for (int dy = 0; dy < 7; ++dy) {
        float4 xv = x4[(r0 + dy) * 64 + l];
        float4 yv = y4[(r0 + dy) * 64 + l];
        accum4(sx, sy, sq, sxy, xv, yv);
    }

    // stage slide-0 loads (rows r0, r0+7)
    float4 cxo = x4[r0 * 64 + l],       cyo = y4[r0 * 64 + l];
    float4 cxn = x4[(r0 + 7) * 64 + l], cyn = y4[(r0 + 7) * 64 + l];

    float acc = 0.f;
#pragma unroll
    for (int it = 0; it < RPS; ++it) {
        // stage slide-(it+1) loads one full iteration ahead of use
        float4 nxo, nyo, nxn, nyn;
        if (it < RPS - 2) {
            int rr = r0 + it + 1;
            nxo = x4[rr * 64 + l];       nyo = y4[rr * 64 + l];
            nxn = x4[(rr + 7) * 64 + l]; nyn = y4[(rr + 7) * 64 + l];
        }
        // pin load issue point: loads above cannot sink below this fence
        asm volatile("" ::: "memory");

        float4 hx  = taps7_bp(sx,  a1, a2);
        float4 hy  = taps7_bp(sy,  a1, a2);
        float4 hq  = taps7_bp(sq,  a1, a2);
        float4 hxy = taps7_bp(sxy, a1, a2);

        // lanes 0..61: all 4 valid; lane 62 (c0=248): 2 valid; lane 63: none
        if (c0 + 0 < OUTW) acc += ssim_px4(hx.x, hy.x, hq.x, hxy.x, c1, c2);
        if (c0 + 1 < OUTW) acc += ssim_px4(hx.y, hy.y, hq.y, hxy.y, c1, c2);
        if (c0 + 2 < OUTW) acc += ssim_px4(hx.z, hy.z, hq.z, hxy.z, c1, c2);
        if (c0 + 3 < OUTW) acc += ssim_px4(hx.w, hy.w, hq.w, hxy.w, c1, c2);

        if (it < RPS - 1)
            slide4(sx, sy, sq, sxy, cxo, cyo, cxn, cyn);
        if (it < RPS - 2) {      // rotate staged set for the next slide
            cxo = nxo; cyo = nyo; cxn = nxn; cyn = nyn;
        }
    }

    // block-level reduction: 4 waves -> 1 partial per block
    acc = wave_sum(acc);
    __shared__ float ssum[4];
    if (l == 0) ssum[w] = acc;
    __syncthreads();
    if (threadIdx.x == 0)
        partials[blockIdx.x] = (ssum[0] + ssum[1]) + (ssum[2] + ssum[3]);
}

// ---------------- Pass 3: final reduce ----------------
__global__ __launch_bounds__(256) void final_kernel(const float* __restrict__ partials,
                                                    float* __restrict__ out) {
    float s = 0.f;
    for (int i = threadIdx.x; i < NBLK2; i += 256) s += partials[i];
    s = wave_sum(s);
    __shared__ float ssum[4];
    int lane = threadIdx.x & 63, w = threadIdx.x >> 6;
    if (lane == 0) ssum[w] = s;
    __syncthreads();
    if (threadIdx.x == 0) {
        float total = ssum[0] + ssum[1] + ssum[2] + ssum[3];
        const double denom = (double)NFRAMES * OUTW * OUTW;
        out[0] = (float)(1.0 - (double)total / denom);
    }
}

extern "C" void kernel_launch(void* const* d_in, const int* in_sizes, int n_in,
                              void* d_out, int out_size, void* d_ws, size_t ws_size,
                              hipStream_t stream) {
    const float* X = (const float*)d_in[0];
    const float* Y = (const float*)d_in[1];

    float* ws = (float*)d_ws;
    float* dr_part  = ws;                // [0 .. 1280)
    float* partials = ws + 2048;         // [2048 .. 2048+4000)

    dim3 g1(NT, NB * 4);
    hipLaunchKernelGGL(dr_max_kernel, g1, dim3(256), 0, stream, Y, dr_part);
    hipLaunchKernelGGL(ssim_kernel, dim3(NBLK2), dim3(256), 0, stream,
                       X, Y, (const float*)dr_part, partials);
    hipLaunchKernelGGL(final_kernel, dim3(1), dim3(256), 0, stream,
                       partials, (float*)d_out);
}

// Round 9
// 198.519 us; speedup vs baseline: 1.0617x; 1.0131x over previous
//
#include <hip/hip_runtime.h>

// SSIM loss: Xt, Yt are [B=16, C=1, T=20, H=256, W=256] fp32.
// Frame f = b*20 + t contiguous 65536 floats. dr[t] = max over Yt[:,:,t].
// S per 7x7 valid window (250x250/frame); out = 1 - mean(S).

#define HH 256
#define WW 256
#define OUTW 250
#define NT 20
#define NB 16
#define NFRAMES (NT * NB)        // 320
#define STRIPS 50
#define RPS 5                    // output rows per strip (50*5 = 250)
#define NWAVES (NFRAMES * STRIPS) // 16000
#define WPB 8                    // waves per block (R14: 512-thread blocks)
#define NBLK2 (NWAVES / WPB)     // 2000
#define NXCD 8

__device__ __forceinline__ float wave_sum(float v) {
#pragma unroll
    for (int off = 32; off > 0; off >>= 1) v += __shfl_down(v, off, 64);
    return v;
}

// ---------------- Pass 1: per-t max over Yt (quarter-frame blocks) ----------
__global__ __launch_bounds__(256) void dr_max_kernel(const float* __restrict__ Y,
                                                     float* __restrict__ dr_part) {
    int t = blockIdx.x;          // 0..19
    int bq = blockIdx.y;         // 0..63 : b = bq>>2, quarter = bq&3
    const float4* p = (const float4*)(Y + (size_t)((bq >> 2) * NT + t) * (HH * WW))
                      + (bq & 3) * 4096;
    float m = 0.f;               // inputs uniform [0,1) => non-negative
#pragma unroll 4
    for (int k = 0; k < 16; ++k) {
        float4 v = p[k * 256 + threadIdx.x];
        m = fmaxf(m, fmaxf(fmaxf(v.x, v.y), fmaxf(v.z, v.w)));
    }
#pragma unroll
    for (int off = 32; off > 0; off >>= 1) m = fmaxf(m, __shfl_down(m, off, 64));
    __shared__ float smax[4];
    int lane = threadIdx.x & 63, w = threadIdx.x >> 6;
    if (lane == 0) smax[w] = m;
    __syncthreads();
    if (threadIdx.x == 0)
        dr_part[t * 64 + bq] = fmaxf(fmaxf(smax[0], smax[1]), fmaxf(smax[2], smax[3]));
}

// ---------------- Pass 2: SSIM ------------------------------------------
// R14: single-variable residency experiment. R13's inner loop byte-for-byte
// (4 moments, raw ds_bpermute w/ hoisted addrs, 2-deep staged loads, XCD
// swizzle) but WPB 4->8 (512-thread blocks). Evidence: 8 structures pinned
// at 52-60us; occupancy never exceeds ~13 waves/CU (~3 blocks/CU) although
// VGPR 52 / LDS 512B permit 32 waves/CU => suspected per-CU BLOCK-count cap.
// Bigger blocks buy waves/CU directly if the cap is per-block.
// __launch_bounds__(512,4): same VGPR<=128 allocator budget as proven code.

// S scaled by 49^2 top & bottom (cancels): c1=2401*C1, c2=2401*C2.
// 4-moment form: B2 = cov*(49*hq - hx^2 - hy^2) + c2, hq = 7-tap of sxx+syy.
__device__ __forceinline__ float ssim_px4(float hx, float hy, float hq,
                                          float hxy, float c1, float c2) {
    const float cov = 49.0f / 48.0f;
    float hx2 = hx * hx, hy2 = hy * hy, hxy1 = hx * hy;
    float s2 = hx2 + hy2;
    float A1 = __builtin_fmaf(2.f, hxy1, c1);
    float B1 = s2 + c1;
    float t12 = __builtin_fmaf(49.f, hq, -s2);
    float t3  = __builtin_fmaf(49.f, hxy, -hxy1);
    float A2 = __builtin_fmaf(2.f * cov, t3, c2);
    float B2 = __builtin_fmaf(cov, t12, c2);
    return (A1 * A2) * __builtin_amdgcn_rcpf(B1 * B2);
}

__device__ __forceinline__ float bperm(int addr, float v) {
    return __int_as_float(__builtin_amdgcn_ds_bpermute(addr, __float_as_int(v)));
}

// 7-tap horizontal sums for 4 consecutive output cols; a1/a2 = byte addrs of
// lanes l+1, l+2 (clamped to 63; clamped values feed only masked outputs).
//   P = s.x+s.y+s.z+s.w;  P1 = P(l+1), w1 = s.w(l+1), x2 = s.x(l+2), y2 = s.y(l+2)
//   o0 = P+P1-w1; o1 = P+P1-s.x; o2 = s.z+s.w+P1+x2; o3 = s.w+P1+x2+y2
__device__ __forceinline__ float4 taps7_bp(float4 s, int a1, int a2) {
    float P  = (s.x + s.y) + (s.z + s.w);
    float P1 = bperm(a1, P);
    float w1 = bperm(a1, s.w);
    float x2 = bperm(a2, s.x);
    float y2 = bperm(a2, s.y);
    float base = P + P1;
    float o0 = base - w1;
    float o1 = base - s.x;
    float o2 = s.z + s.w + P1 + x2;
    float o3 = o2 - s.z + y2;          // s.w + P1 + x2 + y2
    return make_float4(o0, o1, o2, o3);
}

// slide with (xn-xo)*(xn+xo) factorization; sq accumulates xx+yy deltas
__device__ __forceinline__ void slide4(float4& sx, float4& sy, float4& sq,
                                       float4& sxy,
                                       float4 xo, float4 yo, float4 xn, float4 yn) {
    float dx, ex, dy, ey;
    dx = xn.x - xo.x; ex = xn.x + xo.x; sx.x += dx; sq.x = __builtin_fmaf(dx, ex, sq.x);
    dy = yn.x - yo.x; ey = yn.x + yo.x; sy.x += dy; sq.x = __builtin_fmaf(dy, ey, sq.x);
    sxy.x += xn.x * yn.x - xo.x * yo.x;
    dx = xn.y - xo.y; ex = xn.y + xo.y; sx.y += dx; sq.y = __builtin_fmaf(dx, ex, sq.y);
    dy = yn.y - yo.y; ey = yn.y + yo.y; sy.y += dy; sq.y = __builtin_fmaf(dy, ey, sq.y);
    sxy.y += xn.y * yn.y - xo.y * yo.y;
    dx = xn.z - xo.z; ex = xn.z + xo.z; sx.z += dx; sq.z = __builtin_fmaf(dx, ex, sq.z);
    dy = yn.z - yo.z; ey = yn.z + yo.z; sy.z += dy; sq.z = __builtin_fmaf(dy, ey, sq.z);
    sxy.z += xn.z * yn.z - xo.z * yo.z;
    dx = xn.w - xo.w; ex = xn.w + xo.w; sx.w += dx; sq.w = __builtin_fmaf(dx, ex, sq.w);
    dy = yn.w - yo.w; ey = yn.w + yo.w; sy.w += dy; sq.w = __builtin_fmaf(dy, ey, sq.w);
    sxy.w += xn.w * yn.w - xo.w * yo.w;
}

__device__ __forceinline__ void accum4(float4& sx, float4& sy, float4& sq,
                                       float4& sxy, float4 xv, float4 yv) {
    sx.x += xv.x; sx.y += xv.y; sx.z += xv.z; sx.w += xv.w;
    sy.x += yv.x; sy.y += yv.y; sy.z += yv.z; sy.w += yv.w;
    sq.x = __builtin_fmaf(xv.x, xv.x, sq.x); sq.x = __builtin_fmaf(yv.x, yv.x, sq.x);
    sq.y = __builtin_fmaf(xv.y, xv.y, sq.y); sq.y = __builtin_fmaf(yv.y, yv.y, sq.y);
    sq.z = __builtin_fmaf(xv.z, xv.z, sq.z); sq.z = __builtin_fmaf(yv.z, yv.z, sq.z);
    sq.w = __builtin_fmaf(xv.w, xv.w, sq.w); sq.w = __builtin_fmaf(yv.w, yv.w, sq.w);
    sxy.x = __builtin_fmaf(xv.x, yv.x, sxy.x); sxy.y = __builtin_fmaf(xv.y, yv.y, sxy.y);
    sxy.z = __builtin_fmaf(xv.z, yv.z, sxy.z); sxy.w = __builtin_fmaf(xv.w, yv.w, sxy.w);
}

__global__ __launch_bounds__(512, 4) void ssim_kernel(const float* __restrict__ X,
                                                      const float* __restrict__ Y,
                                                      const float* __restrict__ dr_part,
                                                      float* __restrict__ partials) {
    int w = threadIdx.x >> 6;   // 0..7
    int l = threadIdx.x & 63;
    // Bijective XCD swizzle (NBLK2 % 8 == 0)
    int bid = blockIdx.x;
    int swz = (bid % NXCD) * (NBLK2 / NXCD) + bid / NXCD;
    int wid = swz * WPB + w;
    int frame = wid / STRIPS;   // 0..319
    int strip = wid % STRIPS;   // 0..49
    int t = frame % NT;
    const float4* x4 = (const float4*)(X + (size_t)frame * (HH * WW));
    const float4* y4 = (const float4*)(Y + (size_t)frame * (HH * WW));
    int c0 = 4 * l;
    // hoisted bpermute byte-addresses (loop-invariant)
    int a1 = (l < 63 ? l + 1 : 63) << 2;
    int a2 = (l < 62 ? l + 2 : 63) << 2;

    // dr[t] = max of the 64 per-block partial maxes (one per lane, butterfly)
    float dr = dr_part[t * 64 + l];
#pragma unroll
    for (int off = 32; off > 0; off >>= 1) dr = fmaxf(dr, __shfl_xor(dr, off, 64));
    float c1 = 2401.f * (0.01f * dr) * (0.01f * dr);
    float c2 = 2401.f * (0.03f * dr) * (0.03f * dr);

    int r0 = strip * RPS;

    // vertical running column-sums (4 cols/lane) over rows r0..r0+6
    float4 sx = make_float4(0, 0, 0, 0), sy = sx, sq = sx, sxy = sx;
#pragma unroll
    for (int dy = 0; dy < 7; ++dy) {
        float4 xv = x4[(r0 + dy) * 64 + l];
        float4 yv = y4[(r0 + dy) * 64 + l];
        accum4(sx, sy, sq, sxy, xv, yv);
    }

    // stage slide-0 loads (rows r0, r0+7)
    float4 cxo = x4[r0 * 64 + l],       cyo = y4[r0 * 64 + l];
    float4 cxn = x4[(r0 + 7) * 64 + l], cyn = y4[(r0 + 7) * 64 + l];

    float acc = 0.f;
#pragma unroll
    for (int it = 0; it < RPS; ++it) {
        // stage slide-(it+1) loads one full iteration ahead of use
        float4 nxo, nyo, nxn, nyn;
        if (it < RPS - 2) {
            int rr = r0 + it + 1;
            nxo = x4[rr * 64 + l];       nyo = y4[rr * 64 + l];
            nxn = x4[(rr + 7) * 64 + l]; nyn = y4[(rr + 7) * 64 + l];
        }
        // pin load issue point: loads above cannot sink below this fence
        asm volatile("" ::: "memory");

        float4 hx  = taps7_bp(sx,  a1, a2);
        float4 hy  = taps7_bp(sy,  a1, a2);
        float4 hq  = taps7_bp(sq,  a1, a2);
        float4 hxy = taps7_bp(sxy, a1, a2);

        // lanes 0..61: all 4 valid; lane 62 (c0=248): 2 valid; lane 63: none
        if (c0 + 0 < OUTW) acc += ssim_px4(hx.x, hy.x, hq.x, hxy.x, c1, c2);
        if (c0 + 1 < OUTW) acc += ssim_px4(hx.y, hy.y, hq.y, hxy.y, c1, c2);
        if (c0 + 2 < OUTW) acc += ssim_px4(hx.z, hy.z, hq.z, hxy.z, c1, c2);
        if (c0 + 3 < OUTW) acc += ssim_px4(hx.w, hy.w, hq.w, hxy.w, c1, c2);

        if (it < RPS - 1)
            slide4(sx, sy, sq, sxy, cxo, cyo, cxn, cyn);
        if (it < RPS - 2) {      // rotate staged set for the next slide
            cxo = nxo; cyo = nyo; cxn = nxn; cyn = nyn;
        }
    }

    // block-level reduction: 8 waves -> 1 partial per block
    acc = wave_sum(acc);
    __shared__ float ssum[WPB];
    if (l == 0) ssum[w] = acc;
    __syncthreads();
    if (threadIdx.x == 0) {
        float s = 0.f;
#pragma unroll
        for (int i = 0; i < WPB; ++i) s += ssum[i];
        partials[blockIdx.x] = s;
    }
}

// ---------------- Pass 3: final reduce ----------------
__global__ __launch_bounds__(256) void final_kernel(const float* __restrict__ partials,
                                                    float* __restrict__ out) {
    float s = 0.f;
    for (int i = threadIdx.x; i < NBLK2; i += 256) s += partials[i];
    s = wave_sum(s);
    __shared__ float ssum[4];
    int lane = threadIdx.x & 63, w = threadIdx.x >> 6;
    if (lane == 0) ssum[w] = s;
    __syncthreads();
    if (threadIdx.x == 0) {
        float total = ssum[0] + ssum[1] + ssum[2] + ssum[3];
        const double denom = (double)NFRAMES * OUTW * OUTW;
        out[0] = (float)(1.0 - (double)total / denom);
    }
}

extern "C" void kernel_launch(void* const* d_in, const int* in_sizes, int n_in,
                              void* d_out, int out_size, void* d_ws, size_t ws_size,
                              hipStream_t stream) {
    const float* X = (const float*)d_in[0];
    const float* Y = (const float*)d_in[1];

    float* ws = (float*)d_ws;
    float* dr_part  = ws;                // [0 .. 1280)
    float* partials = ws + 2048;         // [2048 .. 2048+2000)

    dim3 g1(NT, NB * 4);
    hipLaunchKernelGGL(dr_max_kernel, g1, dim3(256), 0, stream, Y, dr_part);
    hipLaunchKernelGGL(ssim_kernel, dim3(NBLK2), dim3(512), 0, stream,
                       X, Y, (const float*)dr_part, partials);
    hipLaunchKernelGGL(final_kernel, dim3(1), dim3(256), 0, stream,
                       partials, (float*)d_out);
}